// Round 10
// baseline (99.297 us; speedup 1.0000x reference)
//
#include <hip/hip_runtime.h>
#include <hip/hip_bf16.h>
#include <math.h>

#define BATCH 4
#define CH    256
#define NPOS  4096
#define DQK   32
#define LOG2E 1.4426950408889634f
#define QB2   (-28.853900817779268f)   // -20 * log2(e): p = exp2(S*log2e + QB2) = exp(S-20)

typedef __attribute__((ext_vector_type(8))) short bf16x8;
typedef __attribute__((ext_vector_type(4))) float f32x4;

static __device__ __forceinline__ unsigned int pack_bf2(float a, float b) {
    __hip_bfloat162 h = __float22bfloat162_rn(make_float2(a, b));
    return *reinterpret_cast<unsigned int*>(&h);
}
static __device__ __forceinline__ unsigned short f2bf1(float f) {
    unsigned int u = __float_as_uint(f);
    u += 0x7fff + ((u >> 16) & 1);
    return (unsigned short)(u >> 16);
}
static __device__ __forceinline__ bf16x8 pack8(const float* v) {
    bf16x8 r;
    #pragma unroll
    for (int j = 0; j < 8; ++j) r[j] = (short)f2bf1(v[j]);
    return r;
}

// Barrier WITHOUT the vmcnt(0) drain: LDS ops must be complete (cross-wave
// visibility), but register-destined global prefetches stay in flight.
static __device__ __forceinline__ void lds_barrier() {
    asm volatile("s_waitcnt lgkmcnt(0)" ::: "memory");
    __builtin_amdgcn_s_barrier();
    asm volatile("" ::: "memory");
}

// ---------------- Kernel 1: MFMA projection GEMM ----------------
// q is pre-scaled by log2(e) so the flash kernel can use a single v_exp_f32.
__global__ __launch_bounds__(256) void qkv_proj_mfma(
    const float* __restrict__ x,
    const float* __restrict__ Wq, const float* __restrict__ bq,
    const float* __restrict__ Wk, const float* __restrict__ bk,
    const float* __restrict__ Wv, const float* __restrict__ bv,
    __hip_bfloat16* __restrict__ qb, __hip_bfloat16* __restrict__ kb,
    __hip_bfloat16* __restrict__ vb)
{
    const int tid  = threadIdx.x;
    const int wave = tid >> 6, lane = tid & 63;
    const int g    = lane >> 4, lm = lane & 15;
    const int n0   = blockIdx.x * 32;
    const int b    = blockIdx.y;
    const float* xb = x + (size_t)b * CH * NPOS;

    bf16x8 xf[2][8];
    #pragma unroll
    for (int nt = 0; nt < 2; ++nt)
        #pragma unroll
        for (int kt = 0; kt < 8; ++kt) {
            const float* p = xb + (32 * kt + 8 * g) * NPOS + n0 + 16 * nt + lm;
            float v[8];
            #pragma unroll
            for (int j = 0; j < 8; ++j) v[j] = p[j * NPOS];
            xf[nt][kt] = pack8(v);
        }

    #pragma unroll
    for (int s = 0; s < 5; ++s) {
        const int cot = wave * 5 + s;
        const float* Wsrc; const float* bsrc; int cbase; int kind;
        if (cot < 2)      { Wsrc = Wq; bsrc = bq; cbase = cot * 16;      kind = 0; }
        else if (cot < 4) { Wsrc = Wk; bsrc = bk; cbase = cot * 16 - 32; kind = 1; }
        else              { Wsrc = Wv; bsrc = bv; cbase = cot * 16 - 64; kind = 2; }

        bf16x8 wf[8];
        const float* wrow = Wsrc + (size_t)(cbase + lm) * CH;
        #pragma unroll
        for (int kt = 0; kt < 8; ++kt) {
            float4 wa = *(const float4*)(wrow + 32 * kt + 8 * g);
            float4 wc = *(const float4*)(wrow + 32 * kt + 8 * g + 4);
            float wv[8] = {wa.x, wa.y, wa.z, wa.w, wc.x, wc.y, wc.z, wc.w};
            wf[kt] = pack8(wv);
        }
        const float4 b4 = *(const float4*)(bsrc + cbase + 4 * g);
        f32x4 a0 = {b4.x, b4.y, b4.z, b4.w};
        f32x4 a1 = a0;
        #pragma unroll
        for (int kt = 0; kt < 8; ++kt) {
            a0 = __builtin_amdgcn_mfma_f32_16x16x32_bf16(wf[kt], xf[0][kt], a0, 0, 0, 0);
            a1 = __builtin_amdgcn_mfma_f32_16x16x32_bf16(wf[kt], xf[1][kt], a1, 0, 0, 0);
        }
        if (kind == 0) {
            #pragma unroll
            for (int r = 0; r < 4; ++r) { a0[r] *= LOG2E; a1[r] *= LOG2E; }
        }

        if (kind <= 1) {
            __hip_bfloat16* dst = (kind == 0 ? qb : kb);
            #pragma unroll
            for (int nt = 0; nt < 2; ++nt) {
                f32x4 a = nt ? a1 : a0;
                int n = n0 + 16 * nt + lm;
                uint2 w;
                w.x = pack_bf2(a[0], a[1]);
                w.y = pack_bf2(a[2], a[3]);
                *(uint2*)(dst + ((size_t)b * NPOS + n) * DQK + cbase + 4 * g) = w;
            }
        } else {
            #pragma unroll
            for (int nt = 0; nt < 2; ++nt) {
                f32x4 a = nt ? a1 : a0;
                int n = n0 + 16 * nt + lm;
                int n64 = n >> 6, half = (n >> 5) & 1, nin = n & 31;
                #pragma unroll
                for (int r = 0; r < 4; ++r) {
                    int c = cbase + 4 * g + r;
                    size_t off = (((size_t)b * 16 + (c >> 4)) * 64 + n64) * 1024
                               + (size_t)half * 512 + (c & 15) * 32 + nin;
                    *reinterpret_cast<unsigned short*>(vb + off) = f2bf1(a[r]);
                }
            }
        }
    }
}

// ---------------- Kernel 2: cooperative MFMA flash, M=32, 4-wave blocks ----------------
// grid 512 (2 blocks/CU): b = bid&3 (one batch per XCD), m0 = (bid>>2)*32.
// block 256 = 4 waves; wave w: QK subtiles (kt=w, mt=0/1) -> exp2 -> P LDS;
// PV: channels [64w, 64w+64) x all 32 m. Per-wave work identical to R8; two
// independent barrier domains per CU cover each other's stalls.
__global__ __launch_bounds__(256, 2) void flash_pam_kernel(
    const __hip_bfloat16* __restrict__ qb, const __hip_bfloat16* __restrict__ kb,
    const __hip_bfloat16* __restrict__ vb, const float* __restrict__ x,
    const float* __restrict__ gamma, float* __restrict__ out)
{
    __shared__ alignas(16) unsigned char Pl[2][4096];  // [parity][32m x 128B]
    __shared__ float lred[4][2][16];                   // [kt][mt][lm]

    const int tid  = threadIdx.x;
    const int wave = tid >> 6;      // 0..3: kt for QK, ch-group for PV
    const int lane = tid & 63;
    const int g    = lane >> 4;
    const int lm   = lane & 15;
    const int bid  = blockIdx.x;
    const int b    = bid & 3;
    const int m0   = (bid >> 2) * 32;
    const unsigned swz = (unsigned)(lm & 7) << 4;

    const bf16x8 qfA = *reinterpret_cast<const bf16x8*>(
        qb + ((size_t)b * NPOS + m0 + lm) * DQK + 8 * g);
    const bf16x8 qfB = *reinterpret_cast<const bf16x8*>(
        qb + ((size_t)b * NPOS + m0 + 16 + lm) * DQK + 8 * g);

    const __hip_bfloat16* kbb = kb + (size_t)b * NPOS * DQK;
    const int koff0 = (16 * wave + lm) * DQK + 8 * g;         // + t*2048
    const __hip_bfloat16* vbb = vb + (size_t)b * 16 * 64 * 1024;
    int vfb[8];                                               // + t*1024
    #pragma unroll
    for (int ct = 0; ct < 4; ++ct)
        #pragma unroll
        for (int kc = 0; kc < 2; ++kc)
            vfb[2 * ct + kc] = (4 * wave + ct) * 65536 + kc * 512 + lm * 32 + 8 * g;

    const unsigned wbA = (unsigned)lm * 128 + (((unsigned)(32 * wave + 8 * g)) ^ swz);
    const unsigned wbB = wbA + 2048;   // mt=1 rows 16..31

    unsigned char* P0 = &Pl[0][0];
    unsigned char* P1 = &Pl[1][0];

    f32x4 acc[4][2];
    #pragma unroll
    for (int i = 0; i < 4; ++i)
        #pragma unroll
        for (int j = 0; j < 2; ++j) acc[i][j] = (f32x4){0.f, 0.f, 0.f, 0.f};
    float lsA = 0.f, lsB = 0.f;

#define LOADK(dst, tk_) \
    dst = *reinterpret_cast<const bf16x8*>(kbb + koff0 + (tk_) * 2048);

#define LOADV8(dst, tv_) { \
    _Pragma("unroll") for (int f = 0; f < 8; ++f) \
        dst[f] = *reinterpret_cast<const bf16x8*>(vbb + vfb[f] + (tv_) * 1024); }

#define QKW(KU, PW) { \
    f32x4 zb = {QB2, QB2, QB2, QB2}; \
    f32x4 sA = __builtin_amdgcn_mfma_f32_16x16x32_bf16(KU, qfA, zb, 0, 0, 0); \
    f32x4 sB = __builtin_amdgcn_mfma_f32_16x16x32_bf16(KU, qfB, zb, 0, 0, 0); \
    { float p0 = exp2f(sA[0]), p1 = exp2f(sA[1]); \
      float p2 = exp2f(sA[2]), p3 = exp2f(sA[3]); \
      lsA += (p0 + p1) + (p2 + p3); \
      uint2 w; w.x = pack_bf2(p0, p1); w.y = pack_bf2(p2, p3); \
      *reinterpret_cast<uint2*>((PW) + wbA) = w; } \
    { float p0 = exp2f(sB[0]), p1 = exp2f(sB[1]); \
      float p2 = exp2f(sB[2]), p3 = exp2f(sB[3]); \
      lsB += (p0 + p1) + (p2 + p3); \
      uint2 w; w.x = pack_bf2(p0, p1); w.y = pack_bf2(p2, p3); \
      *reinterpret_cast<uint2*>((PW) + wbB) = w; } }

#define PVt(PR, VR) { \
    _Pragma("unroll") for (int kc = 0; kc < 2; ++kc) { \
        bf16x8 pf0 = *reinterpret_cast<const bf16x8*>( \
            (PR) + (unsigned)lm * 128 + (((unsigned)(kc * 64 + 16 * g)) ^ swz)); \
        bf16x8 pf1 = *reinterpret_cast<const bf16x8*>( \
            (PR) + 2048 + (unsigned)lm * 128 + (((unsigned)(kc * 64 + 16 * g)) ^ swz)); \
        __builtin_amdgcn_s_setprio(1); \
        _Pragma("unroll") for (int ct = 0; ct < 4; ++ct) { \
            acc[ct][0] = __builtin_amdgcn_mfma_f32_16x16x32_bf16( \
                VR[2 * ct + kc], pf0, acc[ct][0], 0, 0, 0); \
            acc[ct][1] = __builtin_amdgcn_mfma_f32_16x16x32_bf16( \
                VR[2 * ct + kc], pf1, acc[ct][1], 0, 0, 0); } \
        __builtin_amdgcn_s_setprio(0); } }

// BODY(t): prefetch V(t+1),K(t+2); QK(t+1)+exp -> PW; PV(t) from PR+VR; raw barrier.
#define BODY(t_, PR, PW, VR, VL, KU, KL) { \
    { int tv = (t_) + 1; if (tv > 63) tv = 63; LOADV8(VL, tv); } \
    { int tk2 = (t_) + 2; if (tk2 > 63) tk2 = 63; LOADK(KL, tk2); } \
    QKW(KU, PW); \
    PVt(PR, VR); \
    lds_barrier(); }

    // prologue
    bf16x8 kA, kB, vA[8], vB[8];
    LOADK(kA, 0);
    LOADV8(vA, 0);
    LOADK(kB, 1);
    QKW(kA, P0);
    lds_barrier();

    for (int it = 0; it < 31; ++it) {
        BODY(2 * it,     P0, P1, vA, vB, kB, kA);
        BODY(2 * it + 1, P1, P0, vB, vA, kA, kB);
    }
    BODY(62, P0, P1, vA, vB, kB, kA);
    PVt(P1, vB);   // t = 63

    // merge per-subtile l partials: reduce over g in-wave, over kt via LDS
    lsA += __shfl_xor(lsA, 16); lsA += __shfl_xor(lsA, 32);
    lsB += __shfl_xor(lsB, 16); lsB += __shfl_xor(lsB, 32);
    if (lane < 16) {
        lred[wave][0][lm] = lsA;
        lred[wave][1][lm] = lsB;
    }
    __syncthreads();

    float linv[2];
    #pragma unroll
    for (int mt = 0; mt < 2; ++mt)
        linv[mt] = 1.f / (lred[0][mt][lm] + lred[1][mt][lm]
                        + lred[2][mt][lm] + lred[3][mt][lm]);

    const float gmv = gamma[0];
    #pragma unroll
    for (int ct = 0; ct < 4; ++ct)
        #pragma unroll
        for (int mt = 0; mt < 2; ++mt)
            #pragma unroll
            for (int r = 0; r < 4; ++r) {
                int c = 64 * wave + 16 * ct + 4 * g + r;
                size_t idx = ((size_t)b * CH + c) * NPOS + m0 + 16 * mt + lm;
                out[idx] = gmv * (acc[ct][mt][r] * linv[mt]) + x[idx];
            }
#undef BODY
#undef PVt
#undef QKW
#undef LOADV8
#undef LOADK
}

extern "C" void kernel_launch(void* const* d_in, const int* in_sizes, int n_in,
                              void* d_out, int out_size, void* d_ws, size_t ws_size,
                              hipStream_t stream) {
    const float* x  = (const float*)d_in[0];
    const float* Wq = (const float*)d_in[1];
    const float* bq = (const float*)d_in[2];
    const float* Wk = (const float*)d_in[3];
    const float* bk = (const float*)d_in[4];
    const float* Wv = (const float*)d_in[5];
    const float* bv = (const float*)d_in[6];
    const float* gm = (const float*)d_in[7];
    float* out = (float*)d_out;

    __hip_bfloat16* qbuf = (__hip_bfloat16*)d_ws;
    __hip_bfloat16* kbuf = qbuf + (size_t)BATCH * NPOS * DQK;
    __hip_bfloat16* vbuf = kbuf + (size_t)BATCH * NPOS * DQK;

    qkv_proj_mfma<<<dim3(NPOS / 32, BATCH), 256, 0, stream>>>(
        x, Wq, bq, Wk, bk, Wv, bv, qbuf, kbuf, vbuf);
    flash_pam_kernel<<<dim3(NPOS / 32 * BATCH), 256, 0, stream>>>(
        qbuf, kbuf, vbuf, x, gm, out);
}

// Round 12
// 82.240 us; speedup vs baseline: 1.2074x; 1.2074x over previous
//
#include <hip/hip_runtime.h>
#include <hip/hip_bf16.h>
#include <math.h>

#define BATCH 4
#define CH    256
#define NPOS  4096
#define DQK   32
#define LOG2E 1.4426950408889634f
#define QB2   (-28.853900817779268f)   // -20*log2(e): exp2(S*log2e + QB2) = exp(S-20)

typedef __attribute__((ext_vector_type(8))) short bf16x8;
typedef __attribute__((ext_vector_type(4))) float f32x4;

static __device__ __forceinline__ unsigned int pack_bf2(float a, float b) {
    __hip_bfloat162 h = __float22bfloat162_rn(make_float2(a, b));
    return *reinterpret_cast<unsigned int*>(&h);
}
static __device__ __forceinline__ unsigned short f2bf1(float f) {
    unsigned int u = __float_as_uint(f);
    u += 0x7fff + ((u >> 16) & 1);
    return (unsigned short)(u >> 16);
}
static __device__ __forceinline__ bf16x8 pack8(const float* v) {
    bf16x8 r;
    #pragma unroll
    for (int j = 0; j < 8; ++j) r[j] = (short)f2bf1(v[j]);
    return r;
}

// Barrier WITHOUT the vmcnt(0) drain: LDS ops complete (cross-wave visibility),
// in-flight global->LDS DMAs survive.
static __device__ __forceinline__ void lds_barrier() {
    asm volatile("s_waitcnt lgkmcnt(0)" ::: "memory");
    __builtin_amdgcn_s_barrier();
    asm volatile("" ::: "memory");
}
#define VWAIT0() do { asm volatile("s_waitcnt vmcnt(0)" ::: "memory"); \
                      __builtin_amdgcn_sched_barrier(0); } while (0)
#define LGKM0()  do { asm volatile("s_waitcnt lgkmcnt(0)" ::: "memory"); \
                      __builtin_amdgcn_sched_barrier(0); } while (0)

// Async global->LDS DMA, 16B per lane: dest = lds base (wave-uniform) + lane*16.
static __device__ __forceinline__ void dma16(const __hip_bfloat16* g, unsigned char* l) {
    __builtin_amdgcn_global_load_lds(
        (const __attribute__((address_space(1))) void*)g,
        (__attribute__((address_space(3))) void*)l, 16, 0, 0);
}

// ---------------- Kernel 1: MFMA projection GEMM (q pre-scaled by log2e) ----------------
__global__ __launch_bounds__(256) void qkv_proj_mfma(
    const float* __restrict__ x,
    const float* __restrict__ Wq, const float* __restrict__ bq,
    const float* __restrict__ Wk, const float* __restrict__ bk,
    const float* __restrict__ Wv, const float* __restrict__ bv,
    __hip_bfloat16* __restrict__ qb, __hip_bfloat16* __restrict__ kb,
    __hip_bfloat16* __restrict__ vb)
{
    const int tid  = threadIdx.x;
    const int wave = tid >> 6, lane = tid & 63;
    const int g    = lane >> 4, lm = lane & 15;
    const int n0   = blockIdx.x * 32;
    const int b    = blockIdx.y;
    const float* xb = x + (size_t)b * CH * NPOS;

    bf16x8 xf[2][8];
    #pragma unroll
    for (int nt = 0; nt < 2; ++nt)
        #pragma unroll
        for (int kt = 0; kt < 8; ++kt) {
            const float* p = xb + (32 * kt + 8 * g) * NPOS + n0 + 16 * nt + lm;
            float v[8];
            #pragma unroll
            for (int j = 0; j < 8; ++j) v[j] = p[j * NPOS];
            xf[nt][kt] = pack8(v);
        }

    #pragma unroll
    for (int s = 0; s < 5; ++s) {
        const int cot = wave * 5 + s;
        const float* Wsrc; const float* bsrc; int cbase; int kind;
        if (cot < 2)      { Wsrc = Wq; bsrc = bq; cbase = cot * 16;      kind = 0; }
        else if (cot < 4) { Wsrc = Wk; bsrc = bk; cbase = cot * 16 - 32; kind = 1; }
        else              { Wsrc = Wv; bsrc = bv; cbase = cot * 16 - 64; kind = 2; }

        bf16x8 wf[8];
        const float* wrow = Wsrc + (size_t)(cbase + lm) * CH;
        #pragma unroll
        for (int kt = 0; kt < 8; ++kt) {
            float4 wa = *(const float4*)(wrow + 32 * kt + 8 * g);
            float4 wc = *(const float4*)(wrow + 32 * kt + 8 * g + 4);
            float wv[8] = {wa.x, wa.y, wa.z, wa.w, wc.x, wc.y, wc.z, wc.w};
            wf[kt] = pack8(wv);
        }
        const float4 b4 = *(const float4*)(bsrc + cbase + 4 * g);
        f32x4 a0 = {b4.x, b4.y, b4.z, b4.w};
        f32x4 a1 = a0;
        #pragma unroll
        for (int kt = 0; kt < 8; ++kt) {
            a0 = __builtin_amdgcn_mfma_f32_16x16x32_bf16(wf[kt], xf[0][kt], a0, 0, 0, 0);
            a1 = __builtin_amdgcn_mfma_f32_16x16x32_bf16(wf[kt], xf[1][kt], a1, 0, 0, 0);
        }
        if (kind == 0) {
            #pragma unroll
            for (int r = 0; r < 4; ++r) { a0[r] *= LOG2E; a1[r] *= LOG2E; }
        }

        if (kind <= 1) {
            __hip_bfloat16* dst = (kind == 0 ? qb : kb);
            #pragma unroll
            for (int nt = 0; nt < 2; ++nt) {
                f32x4 a = nt ? a1 : a0;
                int n = n0 + 16 * nt + lm;
                uint2 w;
                w.x = pack_bf2(a[0], a[1]);
                w.y = pack_bf2(a[2], a[3]);
                *(uint2*)(dst + ((size_t)b * NPOS + n) * DQK + cbase + 4 * g) = w;
            }
        } else {
            #pragma unroll
            for (int nt = 0; nt < 2; ++nt) {
                f32x4 a = nt ? a1 : a0;
                int n = n0 + 16 * nt + lm;
                int n64 = n >> 6, half = (n >> 5) & 1, nin = n & 31;
                #pragma unroll
                for (int r = 0; r < 4; ++r) {
                    int c = cbase + 4 * g + r;
                    size_t off = (((size_t)b * 16 + (c >> 4)) * 64 + n64) * 1024
                               + (size_t)half * 512 + (c & 15) * 32 + nin;
                    *reinterpret_cast<unsigned short*>(vb + off) = f2bf1(a[r]);
                }
            }
        }
    }
}

// ---------------- Kernel 2: cooperative flash, V/K staged via global_load_lds ----------------
// R8 geometry: grid 256 (b=bid&3, 64 m-rows), 8 waves. Per tile: VWAIT(0) (DMAs
// issued a full tile ago) -> ds_read V(t)/K(t+1) -> lgkm0 -> issue DMA V(t+1)/K(t+2)
// into wave-private LDS regions -> QK(t+1)+exp2 -> PV(t) -> lgkm-only barrier.
__global__ __launch_bounds__(512) void flash_pam_kernel(
    const __hip_bfloat16* __restrict__ qb, const __hip_bfloat16* __restrict__ kb,
    const __hip_bfloat16* __restrict__ vb, const float* __restrict__ x,
    const float* __restrict__ gamma, float* __restrict__ out)
{
    __shared__ alignas(16) unsigned char Pl[2][8192];
    __shared__ alignas(16) unsigned char Vst[8][4096];
    __shared__ alignas(16) unsigned char Kst[8][1024];
    __shared__ float lred[4][4][16];   // [kt][mt][lm]

    const int tid  = threadIdx.x;
    const int wave = tid >> 6;
    const int lane = tid & 63;
    const int g    = lane >> 4;
    const int lm   = lane & 15;
    const int bid  = blockIdx.x;
    const int b    = bid & 3;
    const int m0   = (bid >> 2) * 64;
    const int kt   = wave & 3;
    const int mtA  = (wave >> 2) * 2;
    const unsigned swz = (unsigned)(lm & 7) << 4;
    const unsigned lane16 = (unsigned)lane * 16;

    const bf16x8 qfA = *reinterpret_cast<const bf16x8*>(
        qb + ((size_t)b * NPOS + m0 + 16 * mtA + lm) * DQK + 8 * g);
    const bf16x8 qfB = *reinterpret_cast<const bf16x8*>(
        qb + ((size_t)b * NPOS + m0 + 16 * mtA + 16 + lm) * DQK + 8 * g);

    // staging sources (per-lane) and wave-private LDS regions
    const __hip_bfloat16* kgl = kb + (size_t)b * NPOS * DQK + (16 * kt + lm) * DQK + 8 * g;
    const __hip_bfloat16* vbb = vb + (size_t)b * 16 * 64 * 1024;
    const __hip_bfloat16* vgl[4];
    #pragma unroll
    for (int cti = 0; cti < 2; ++cti)
        #pragma unroll
        for (int kc = 0; kc < 2; ++kc)
            vgl[2 * cti + kc] = vbb + (2 * wave + cti) * 65536 + kc * 512 + lm * 32 + 8 * g;
    unsigned char* vdst = &Vst[wave][0];
    unsigned char* kdst = &Kst[wave][0];

    const unsigned wbA = (unsigned)(16 * mtA + lm) * 128
                       + (((unsigned)(32 * kt + 8 * g)) ^ swz);
    const unsigned wbB = wbA + 16 * 128;
    unsigned char* P0 = &Pl[0][0];
    unsigned char* P1 = &Pl[1][0];

    f32x4 acc[2][4];
    #pragma unroll
    for (int i = 0; i < 2; ++i)
        #pragma unroll
        for (int j = 0; j < 4; ++j) acc[i][j] = (f32x4){0.f, 0.f, 0.f, 0.f};
    float lsA = 0.f, lsB = 0.f;

#define DMAK(t_) dma16(kgl + (size_t)(t_) * 2048, kdst)
#define DMAV(t_) { \
    _Pragma("unroll") for (int f = 0; f < 4; ++f) \
        dma16(vgl[f] + (size_t)(t_) * 1024, vdst + f * 1024); }
#define READK(dst) dst = *reinterpret_cast<const bf16x8*>(kdst + lane16);
#define READV(dst) { \
    _Pragma("unroll") for (int f = 0; f < 4; ++f) \
        dst[f] = *reinterpret_cast<const bf16x8*>(vdst + f * 1024 + lane16); }

#define QKW(KU, PW) { \
    f32x4 zb = {QB2, QB2, QB2, QB2}; \
    f32x4 sA = __builtin_amdgcn_mfma_f32_16x16x32_bf16(KU, qfA, zb, 0, 0, 0); \
    f32x4 sB = __builtin_amdgcn_mfma_f32_16x16x32_bf16(KU, qfB, zb, 0, 0, 0); \
    { float p0 = exp2f(sA[0]), p1 = exp2f(sA[1]); \
      float p2 = exp2f(sA[2]), p3 = exp2f(sA[3]); \
      lsA += (p0 + p1) + (p2 + p3); \
      uint2 w; w.x = pack_bf2(p0, p1); w.y = pack_bf2(p2, p3); \
      *reinterpret_cast<uint2*>((PW) + wbA) = w; } \
    { float p0 = exp2f(sB[0]), p1 = exp2f(sB[1]); \
      float p2 = exp2f(sB[2]), p3 = exp2f(sB[3]); \
      lsB += (p0 + p1) + (p2 + p3); \
      uint2 w; w.x = pack_bf2(p0, p1); w.y = pack_bf2(p2, p3); \
      *reinterpret_cast<uint2*>((PW) + wbB) = w; } }

#define PVt(PR, VR) { \
    _Pragma("unroll") for (int kc = 0; kc < 2; ++kc) { \
        bf16x8 pf[4]; \
        _Pragma("unroll") for (int mt = 0; mt < 4; ++mt) \
            pf[mt] = *reinterpret_cast<const bf16x8*>( \
                (PR) + (unsigned)(16 * mt + lm) * 128 \
                     + (((unsigned)(kc * 64 + 16 * g)) ^ swz)); \
        __builtin_amdgcn_s_setprio(1); \
        _Pragma("unroll") for (int cti = 0; cti < 2; ++cti) \
            _Pragma("unroll") for (int mt = 0; mt < 4; ++mt) \
                acc[cti][mt] = __builtin_amdgcn_mfma_f32_16x16x32_bf16( \
                    VR[2 * cti + kc], pf[mt], acc[cti][mt], 0, 0, 0); \
        __builtin_amdgcn_s_setprio(0); } }

// BODY(t): wait DMAs (V(t),K(t+1)); read them; fence; issue DMA V(t+1),K(t+2);
// QK(t+1)->PW; PV(t) from PR; lgkm-only barrier.
#define BODY(t_, PR, PW) { \
    VWAIT0(); \
    bf16x8 kreg; READK(kreg); \
    bf16x8 vreg[4]; READV(vreg); \
    LGKM0(); \
    DMAV((t_) + 1); \
    { int tk2 = (t_) + 2; if (tk2 > 63) tk2 = 63; DMAK(tk2); } \
    QKW(kreg, PW); \
    PVt(PR, vreg); \
    lds_barrier(); }

    // prologue: K(0) -> LDS -> reg; issue V(0),K(1); S(0) -> P0
    DMAK(0);
    VWAIT0();
    bf16x8 k0; READK(k0);
    LGKM0();
    DMAV(0);
    DMAK(1);
    QKW(k0, P0);
    lds_barrier();

    for (int it = 0; it < 31; ++it) {
        BODY(2 * it,     P0, P1);
        BODY(2 * it + 1, P1, P0);
    }
    BODY(62, P0, P1);

    // final tile t=63: PV only (P(63) in P1, V(63) staged by BODY(62))
    VWAIT0();
    {
        bf16x8 vreg[4]; READV(vreg);
        PVt(P1, vreg);
    }

    // merge per-subtile l partials: reduce over g in-wave, over kt via LDS
    lsA += __shfl_xor(lsA, 16); lsA += __shfl_xor(lsA, 32);
    lsB += __shfl_xor(lsB, 16); lsB += __shfl_xor(lsB, 32);
    if (lane < 16) {
        lred[kt][mtA][lm]     = lsA;
        lred[kt][mtA + 1][lm] = lsB;
    }
    __syncthreads();

    float linv[4];
    #pragma unroll
    for (int mt = 0; mt < 4; ++mt)
        linv[mt] = 1.f / (lred[0][mt][lm] + lred[1][mt][lm]
                        + lred[2][mt][lm] + lred[3][mt][lm]);

    const float gmv = gamma[0];
    #pragma unroll
    for (int cti = 0; cti < 2; ++cti)
        #pragma unroll
        for (int mt = 0; mt < 4; ++mt)
            #pragma unroll
            for (int r = 0; r < 4; ++r) {
                int c = 32 * wave + 16 * cti + 4 * g + r;
                size_t idx = ((size_t)b * CH + c) * NPOS + m0 + 16 * mt + lm;
                out[idx] = gmv * (acc[cti][mt][r] * linv[mt]) + x[idx];
            }
#undef BODY
#undef PVt
#undef QKW
#undef READV
#undef READK
#undef DMAV
#undef DMAK
}

extern "C" void kernel_launch(void* const* d_in, const int* in_sizes, int n_in,
                              void* d_out, int out_size, void* d_ws, size_t ws_size,
                              hipStream_t stream) {
    const float* x  = (const float*)d_in[0];
    const float* Wq = (const float*)d_in[1];
    const float* bq = (const float*)d_in[2];
    const float* Wk = (const float*)d_in[3];
    const float* bk = (const float*)d_in[4];
    const float* Wv = (const float*)d_in[5];
    const float* bv = (const float*)d_in[6];
    const float* gm = (const float*)d_in[7];
    float* out = (float*)d_out;

    __hip_bfloat16* qbuf = (__hip_bfloat16*)d_ws;
    __hip_bfloat16* kbuf = qbuf + (size_t)BATCH * NPOS * DQK;
    __hip_bfloat16* vbuf = kbuf + (size_t)BATCH * NPOS * DQK;

    qkv_proj_mfma<<<dim3(NPOS / 32, BATCH), 256, 0, stream>>>(
        x, Wq, bq, Wk, bk, Wv, bv, qbuf, kbuf, vbuf);
    flash_pam_kernel<<<dim3(NPOS / 64 * BATCH), 512, 0, stream>>>(
        qbuf, kbuf, vbuf, x, gm, out);
}

// Round 13
// 80.585 us; speedup vs baseline: 1.2322x; 1.0205x over previous
//
#include <hip/hip_runtime.h>
#include <hip/hip_bf16.h>
#include <math.h>

#define BATCH 4
#define CH    256
#define NPOS  4096
#define DQK   32
#define LOG2E 1.4426950408889634f
#define QB2   (-28.853900817779268f)   // -20*log2(e): exp2(S*log2e + QB2) = exp(S-20)

typedef __attribute__((ext_vector_type(8))) short bf16x8;
typedef __attribute__((ext_vector_type(4))) float f32x4;

static __device__ __forceinline__ unsigned int pack_bf2(float a, float b) {
    __hip_bfloat162 h = __float22bfloat162_rn(make_float2(a, b));
    return *reinterpret_cast<unsigned int*>(&h);
}
static __device__ __forceinline__ unsigned short f2bf1(float f) {
    unsigned int u = __float_as_uint(f);
    u += 0x7fff + ((u >> 16) & 1);
    return (unsigned short)(u >> 16);
}
static __device__ __forceinline__ bf16x8 pack8(const float* v) {
    bf16x8 r;
    #pragma unroll
    for (int j = 0; j < 8; ++j) r[j] = (short)f2bf1(v[j]);
    return r;
}

// Barrier WITHOUT the vmcnt(0) drain: LDS ops complete, in-flight
// global->LDS DMAs survive across it.
static __device__ __forceinline__ void lds_barrier() {
    asm volatile("s_waitcnt lgkmcnt(0)" ::: "memory");
    __builtin_amdgcn_s_barrier();
    asm volatile("" ::: "memory");
}
#define VWAIT0() do { asm volatile("s_waitcnt vmcnt(0)" ::: "memory"); \
                      __builtin_amdgcn_sched_barrier(0); } while (0)
#define LGKM0()  do { asm volatile("s_waitcnt lgkmcnt(0)" ::: "memory"); \
                      __builtin_amdgcn_sched_barrier(0); } while (0)

// Async global->LDS DMA, 16B/lane: dest = wave-uniform base + lane*16.
static __device__ __forceinline__ void dma16(const __hip_bfloat16* g, unsigned char* l) {
    __builtin_amdgcn_global_load_lds(
        (const __attribute__((address_space(1))) void*)g,
        (__attribute__((address_space(3))) void*)l, 16, 0, 0);
}

// ---------------- Kernel 1: MFMA projection GEMM (q pre-scaled by log2e) ----------------
__global__ __launch_bounds__(256) void qkv_proj_mfma(
    const float* __restrict__ x,
    const float* __restrict__ Wq, const float* __restrict__ bq,
    const float* __restrict__ Wk, const float* __restrict__ bk,
    const float* __restrict__ Wv, const float* __restrict__ bv,
    __hip_bfloat16* __restrict__ qb, __hip_bfloat16* __restrict__ kb,
    __hip_bfloat16* __restrict__ vb)
{
    const int tid  = threadIdx.x;
    const int wave = tid >> 6, lane = tid & 63;
    const int g    = lane >> 4, lm = lane & 15;
    const int n0   = blockIdx.x * 32;
    const int b    = blockIdx.y;
    const float* xb = x + (size_t)b * CH * NPOS;

    bf16x8 xf[2][8];
    #pragma unroll
    for (int nt = 0; nt < 2; ++nt)
        #pragma unroll
        for (int kt = 0; kt < 8; ++kt) {
            const float* p = xb + (32 * kt + 8 * g) * NPOS + n0 + 16 * nt + lm;
            float v[8];
            #pragma unroll
            for (int j = 0; j < 8; ++j) v[j] = p[j * NPOS];
            xf[nt][kt] = pack8(v);
        }

    #pragma unroll
    for (int s = 0; s < 5; ++s) {
        const int cot = wave * 5 + s;
        const float* Wsrc; const float* bsrc; int cbase; int kind;
        if (cot < 2)      { Wsrc = Wq; bsrc = bq; cbase = cot * 16;      kind = 0; }
        else if (cot < 4) { Wsrc = Wk; bsrc = bk; cbase = cot * 16 - 32; kind = 1; }
        else              { Wsrc = Wv; bsrc = bv; cbase = cot * 16 - 64; kind = 2; }

        bf16x8 wf[8];
        const float* wrow = Wsrc + (size_t)(cbase + lm) * CH;
        #pragma unroll
        for (int kt = 0; kt < 8; ++kt) {
            float4 wa = *(const float4*)(wrow + 32 * kt + 8 * g);
            float4 wc = *(const float4*)(wrow + 32 * kt + 8 * g + 4);
            float wv[8] = {wa.x, wa.y, wa.z, wa.w, wc.x, wc.y, wc.z, wc.w};
            wf[kt] = pack8(wv);
        }
        const float4 b4 = *(const float4*)(bsrc + cbase + 4 * g);
        f32x4 a0 = {b4.x, b4.y, b4.z, b4.w};
        f32x4 a1 = a0;
        #pragma unroll
        for (int kt = 0; kt < 8; ++kt) {
            a0 = __builtin_amdgcn_mfma_f32_16x16x32_bf16(wf[kt], xf[0][kt], a0, 0, 0, 0);
            a1 = __builtin_amdgcn_mfma_f32_16x16x32_bf16(wf[kt], xf[1][kt], a1, 0, 0, 0);
        }
        if (kind == 0) {
            #pragma unroll
            for (int r = 0; r < 4; ++r) { a0[r] *= LOG2E; a1[r] *= LOG2E; }
        }

        if (kind <= 1) {
            __hip_bfloat16* dst = (kind == 0 ? qb : kb);
            #pragma unroll
            for (int nt = 0; nt < 2; ++nt) {
                f32x4 a = nt ? a1 : a0;
                int n = n0 + 16 * nt + lm;
                uint2 w;
                w.x = pack_bf2(a[0], a[1]);
                w.y = pack_bf2(a[2], a[3]);
                *(uint2*)(dst + ((size_t)b * NPOS + n) * DQK + cbase + 4 * g) = w;
            }
        } else {
            #pragma unroll
            for (int nt = 0; nt < 2; ++nt) {
                f32x4 a = nt ? a1 : a0;
                int n = n0 + 16 * nt + lm;
                int n64 = n >> 6, half = (n >> 5) & 1, nin = n & 31;
                #pragma unroll
                for (int r = 0; r < 4; ++r) {
                    int c = cbase + 4 * g + r;
                    size_t off = (((size_t)b * 16 + (c >> 4)) * 64 + n64) * 1024
                               + (size_t)half * 512 + (c & 15) * 32 + nin;
                    *reinterpret_cast<unsigned short*>(vb + off) = f2bf1(a[r]);
                }
            }
        }
    }
}

// ---------------- Kernel 2: producer-consumer MFMA flash ----------------
// grid 256 (b=bid&3, 64 m-rows/block). 8 waves: 0-3 producers (QK+exp2+P),
// 4-7 consumers (PV, 64 ch each, V via global_load_lds 1 tile ahead).
// Each SIMD hosts 1 producer + 1 consumer -> VALU and MFMA pipes overlap.
__global__ __launch_bounds__(512, 2) void flash_pam_kernel(
    const __hip_bfloat16* __restrict__ qb, const __hip_bfloat16* __restrict__ kb,
    const __hip_bfloat16* __restrict__ vb, const float* __restrict__ x,
    const float* __restrict__ gamma, float* __restrict__ out)
{
    __shared__ alignas(16) unsigned char Pl[2][8192];  // [parity][64m x 128B]
    __shared__ alignas(16) unsigned char Vst[4][8192]; // consumer V regions
    __shared__ float lred[4][4][16];                   // [kt][mt][lm]

    const int tid  = threadIdx.x;
    const int wave = tid >> 6;
    const int lane = tid & 63;
    const int g    = lane >> 4;
    const int lm   = lane & 15;
    const int bid  = blockIdx.x;
    const int b    = bid & 3;
    const int m0   = (bid >> 2) * 64;
    const unsigned swz = (unsigned)(lm & 7) << 4;
    const unsigned lane16 = (unsigned)lane * 16;
    unsigned char* P0 = &Pl[0][0];
    unsigned char* P1 = &Pl[1][0];
    const float gmv = gamma[0];

    if (wave < 4) {
        // ================= PRODUCER: kt = wave =================
        const int kt = wave;
        bf16x8 qf[4];
        #pragma unroll
        for (int mt = 0; mt < 4; ++mt)
            qf[mt] = *reinterpret_cast<const bf16x8*>(
                qb + ((size_t)b * NPOS + m0 + 16 * mt + lm) * DQK + 8 * g);
        const __hip_bfloat16* kgl =
            kb + (size_t)b * NPOS * DQK + (16 * kt + lm) * DQK + 8 * g;
        unsigned wb[4];
        #pragma unroll
        for (int mt = 0; mt < 4; ++mt)
            wb[mt] = (unsigned)(16 * mt + lm) * 128
                   + (((unsigned)(32 * kt + 8 * g)) ^ swz);
        float ls[4] = {0.f, 0.f, 0.f, 0.f};

#define QKP(KU, PW) { \
    _Pragma("unroll") for (int mt = 0; mt < 4; ++mt) { \
        f32x4 zb = {QB2, QB2, QB2, QB2}; \
        f32x4 s = __builtin_amdgcn_mfma_f32_16x16x32_bf16(KU, qf[mt], zb, 0, 0, 0); \
        float p0 = exp2f(s[0]), p1 = exp2f(s[1]); \
        float p2 = exp2f(s[2]), p3 = exp2f(s[3]); \
        ls[mt] += (p0 + p1) + (p2 + p3); \
        uint2 w; w.x = pack_bf2(p0, p1); w.y = pack_bf2(p2, p3); \
        *reinterpret_cast<uint2*>((PW) + wb[mt]) = w; } }

        // pre-phase: S(0) -> P0
        bf16x8 k0 = *reinterpret_cast<const bf16x8*>(kgl);
        QKP(k0, P0);
        bf16x8 kcur = *reinterpret_cast<const bf16x8*>(kgl + 2048);   // K(1)
        lds_barrier();

        for (int t = 0; t < 63; ++t) {
            int tn = t + 2; if (tn > 63) tn = 63;
            bf16x8 knext = *reinterpret_cast<const bf16x8*>(kgl + (size_t)tn * 2048);
            QKP(kcur, (t & 1) ? P0 : P1);    // S(t+1) -> buf[(t+1)&1]
            kcur = knext;
            lds_barrier();
        }
#undef QKP
        // l partials: reduce over g-groups, publish per (kt, mt, m)
        #pragma unroll
        for (int mt = 0; mt < 4; ++mt) {
            float v = ls[mt];
            v += __shfl_xor(v, 16);
            v += __shfl_xor(v, 32);
            if (lane < 16) lred[kt][mt][lm] = v;
        }
        lds_barrier();     // match consumers' final barrier
    } else {
        // ================= CONSUMER: channels [64*(wave-4), +64) =================
        const int cw = wave - 4;
        const __hip_bfloat16* vbb = vb + (size_t)b * 16 * 64 * 1024;
        const __hip_bfloat16* vgl[8];
        #pragma unroll
        for (int ct = 0; ct < 4; ++ct)
            #pragma unroll
            for (int kc = 0; kc < 2; ++kc)
                vgl[2 * ct + kc] = vbb + (4 * cw + ct) * 65536 + kc * 512
                                 + lm * 32 + 8 * g;
        unsigned char* vdst = &Vst[cw][0];

        f32x4 acc[4][4];
        #pragma unroll
        for (int i = 0; i < 4; ++i)
            #pragma unroll
            for (int j = 0; j < 4; ++j) acc[i][j] = (f32x4){0.f, 0.f, 0.f, 0.f};

#define DMAV(t_) { \
    _Pragma("unroll") for (int f = 0; f < 8; ++f) \
        dma16(vgl[f] + (size_t)(t_) * 1024, vdst + f * 1024); }

#define PVPHASE(PR) { \
    bf16x8 vreg[8]; \
    _Pragma("unroll") for (int f = 0; f < 8; ++f) \
        vreg[f] = *reinterpret_cast<const bf16x8*>(vdst + f * 1024 + lane16); \
    bf16x8 pf[2][4]; \
    _Pragma("unroll") for (int kc = 0; kc < 2; ++kc) \
        _Pragma("unroll") for (int mt = 0; mt < 4; ++mt) \
            pf[kc][mt] = *reinterpret_cast<const bf16x8*>( \
                (PR) + (unsigned)(16 * mt + lm) * 128 \
                     + (((unsigned)(kc * 64 + 16 * g)) ^ swz)); \
    LGKM0(); \
    DMA_NEXT; \
    __builtin_amdgcn_s_setprio(1); \
    _Pragma("unroll") for (int ct = 0; ct < 4; ++ct) \
        _Pragma("unroll") for (int mt = 0; mt < 4; ++mt) \
            _Pragma("unroll") for (int kc = 0; kc < 2; ++kc) \
                acc[ct][mt] = __builtin_amdgcn_mfma_f32_16x16x32_bf16( \
                    vreg[2 * ct + kc], pf[kc][mt], acc[ct][mt], 0, 0, 0); \
    __builtin_amdgcn_s_setprio(0); }

        DMAV(0);
        lds_barrier();

        for (int t = 0; t < 63; ++t) {
            VWAIT0();                         // V(t) landed
#define DMA_NEXT DMAV(t + 1)
            PVPHASE((t & 1) ? P1 : P0);       // PV(t)
#undef DMA_NEXT
            lds_barrier();
        }
        VWAIT0();                             // V(63)
#define DMA_NEXT
        PVPHASE(P1);                          // PV(63)
#undef DMA_NEXT
        lds_barrier();                        // producers published lred

        float linv[4];
        #pragma unroll
        for (int mt = 0; mt < 4; ++mt)
            linv[mt] = 1.f / (lred[0][mt][lm] + lred[1][mt][lm]
                            + lred[2][mt][lm] + lred[3][mt][lm]);

        #pragma unroll
        for (int ct = 0; ct < 4; ++ct)
            #pragma unroll
            for (int mt = 0; mt < 4; ++mt)
                #pragma unroll
                for (int r = 0; r < 4; ++r) {
                    int c = 64 * cw + 16 * ct + 4 * g + r;
                    size_t idx = ((size_t)b * CH + c) * NPOS + m0 + 16 * mt + lm;
                    out[idx] = gmv * (acc[ct][mt][r] * linv[mt]) + x[idx];
                }
#undef PVPHASE
#undef DMAV
    }
}

extern "C" void kernel_launch(void* const* d_in, const int* in_sizes, int n_in,
                              void* d_out, int out_size, void* d_ws, size_t ws_size,
                              hipStream_t stream) {
    const float* x  = (const float*)d_in[0];
    const float* Wq = (const float*)d_in[1];
    const float* bq = (const float*)d_in[2];
    const float* Wk = (const float*)d_in[3];
    const float* bk = (const float*)d_in[4];
    const float* Wv = (const float*)d_in[5];
    const float* bv = (const float*)d_in[6];
    const float* gm = (const float*)d_in[7];
    float* out = (float*)d_out;

    __hip_bfloat16* qbuf = (__hip_bfloat16*)d_ws;
    __hip_bfloat16* kbuf = qbuf + (size_t)BATCH * NPOS * DQK;
    __hip_bfloat16* vbuf = kbuf + (size_t)BATCH * NPOS * DQK;

    qkv_proj_mfma<<<dim3(NPOS / 32, BATCH), 256, 0, stream>>>(
        x, Wq, bq, Wk, bk, Wv, bv, qbuf, kbuf, vbuf);
    flash_pam_kernel<<<dim3(NPOS / 64 * BATCH), 512, 0, stream>>>(
        qbuf, kbuf, vbuf, x, gm, out);
}

// Round 14
// 72.775 us; speedup vs baseline: 1.3644x; 1.1073x over previous
//
#include <hip/hip_runtime.h>
#include <hip/hip_bf16.h>
#include <math.h>

#define BATCH 4
#define CH    256
#define NPOS  4096
#define DQK   32
#define LOG2E 1.4426950408889634f
#define QB2   (-28.853900817779268f)   // -20*log2(e): exp2(S*log2e + QB2) = exp(S-20)

typedef __attribute__((ext_vector_type(8))) short bf16x8;
typedef __attribute__((ext_vector_type(4))) float f32x4;

static __device__ __forceinline__ unsigned int pack_bf2(float a, float b) {
    __hip_bfloat162 h = __float22bfloat162_rn(make_float2(a, b));
    return *reinterpret_cast<unsigned int*>(&h);
}
static __device__ __forceinline__ unsigned short f2bf1(float f) {
    unsigned int u = __float_as_uint(f);
    u += 0x7fff + ((u >> 16) & 1);
    return (unsigned short)(u >> 16);
}

// Barrier WITHOUT the vmcnt(0) drain.
static __device__ __forceinline__ void lds_barrier() {
    asm volatile("s_waitcnt lgkmcnt(0)" ::: "memory");
    __builtin_amdgcn_s_barrier();
    asm volatile("" ::: "memory");
}

// ---------------- Kernel 0: W -> bf16 (Wq, bq pre-scaled by log2e) ----------------
// Wbf rows: 0-31 = Wq*log2e, 32-63 = Wk, 64-319 = Wv. bcat likewise.
__global__ __launch_bounds__(256) void conv_w(
    const float* __restrict__ Wq, const float* __restrict__ bq,
    const float* __restrict__ Wk, const float* __restrict__ bk,
    const float* __restrict__ Wv, const float* __restrict__ bv,
    __hip_bfloat16* __restrict__ Wbf, float* __restrict__ bcat)
{
    const int co = blockIdx.x;    // 0..319
    const int ci = threadIdx.x;   // 0..255
    const float* src; float scale = 1.f;
    if (co < 32)      { src = Wq + (size_t)co * 256;        scale = LOG2E; }
    else if (co < 64) { src = Wk + (size_t)(co - 32) * 256; }
    else              { src = Wv + (size_t)(co - 64) * 256; }
    *reinterpret_cast<unsigned short*>(Wbf + (size_t)co * 256 + ci) =
        f2bf1(src[ci] * scale);
    if (ci == 0)
        bcat[co] = co < 32 ? bq[co] * LOG2E
                 : (co < 64 ? bk[co - 32] : bv[co - 64]);
}

// ---------------- Kernel 1: MFMA projection GEMM, x staged once via LDS ----------------
// LDS x-tile in MFMA B-fragment layout: frag (nt,kt) slot s holds 8 bf16 of
// column c=32kt+8g+j at n=16nt+lm, with slot s = (g*16+lm) ^ (4kt+g) (XOR
// swizzle -> 32-bank spread on staging writes, conflict-free b128 reads).
__global__ __launch_bounds__(256) void qkv_proj_mfma(
    const float* __restrict__ x,
    const __hip_bfloat16* __restrict__ Wbf, const float* __restrict__ bcat,
    __hip_bfloat16* __restrict__ qb, __hip_bfloat16* __restrict__ kb,
    __hip_bfloat16* __restrict__ vb)
{
    __shared__ alignas(16) unsigned char Xl[16384];
    const int tid  = threadIdx.x;
    const int wave = tid >> 6, lane = tid & 63;
    const int g    = lane >> 4, lm = lane & 15;
    const int n0   = blockIdx.x * 32;
    const int b    = blockIdx.y;

    // ---- stage x-tile (256c x 32n) once: thread t owns row c=t ----
    {
        const int c   = tid;
        const int ktc = c >> 5, gc = (c >> 3) & 3, jc = c & 7;
        const unsigned xw = (unsigned)(4 * ktc + gc);
        const float* xp = x + ((size_t)b * CH + c) * NPOS + n0;
        #pragma unroll
        for (int i = 0; i < 8; ++i) {
            const float4 v4 = reinterpret_cast<const float4*>(xp)[i];
            const float vv[4] = {v4.x, v4.y, v4.z, v4.w};
            #pragma unroll
            for (int e = 0; e < 4; ++e) {
                const int nrel = 4 * i + e;
                const unsigned off =
                    (unsigned)(((nrel >> 4) * 8 + ktc) * 1024)
                  + ((((unsigned)(gc * 16 + (nrel & 15))) ^ xw) * 16)
                  + (unsigned)(jc * 2);
                *reinterpret_cast<unsigned short*>(Xl + off) = f2bf1(vv[e]);
            }
        }
    }
    __syncthreads();

    // ---- fragments from LDS (per-wave, deduped) ----
    bf16x8 xf[2][8];
    #pragma unroll
    for (int nt = 0; nt < 2; ++nt)
        #pragma unroll
        for (int kt = 0; kt < 8; ++kt) {
            const unsigned slot = (unsigned)lane ^ (unsigned)(4 * kt + g);
            xf[nt][kt] = *reinterpret_cast<const bf16x8*>(
                Xl + (unsigned)((nt * 8 + kt) * 1024) + slot * 16);
        }

    #pragma unroll
    for (int s = 0; s < 5; ++s) {
        const int cot = wave * 5 + s;
        const int cog = cot * 16;     // global output-channel row base

        bf16x8 wf[8];
        const __hip_bfloat16* wrow = Wbf + (size_t)(cog + lm) * 256;
        #pragma unroll
        for (int kt = 0; kt < 8; ++kt)
            wf[kt] = *reinterpret_cast<const bf16x8*>(wrow + 32 * kt + 8 * g);

        const float4 b4 = *reinterpret_cast<const float4*>(bcat + cog + 4 * g);
        f32x4 a0 = {b4.x, b4.y, b4.z, b4.w};
        f32x4 a1 = a0;
        #pragma unroll
        for (int kt = 0; kt < 8; ++kt) {
            a0 = __builtin_amdgcn_mfma_f32_16x16x32_bf16(wf[kt], xf[0][kt], a0, 0, 0, 0);
            a1 = __builtin_amdgcn_mfma_f32_16x16x32_bf16(wf[kt], xf[1][kt], a1, 0, 0, 0);
        }

        if (cot < 4) {
            __hip_bfloat16* dst = (cot < 2 ? qb : kb);
            const int cb = (cot < 2 ? cot * 16 : cot * 16 - 32);
            #pragma unroll
            for (int nt = 0; nt < 2; ++nt) {
                f32x4 a = nt ? a1 : a0;
                int n = n0 + 16 * nt + lm;
                uint2 w;
                w.x = pack_bf2(a[0], a[1]);
                w.y = pack_bf2(a[2], a[3]);
                *(uint2*)(dst + ((size_t)b * NPOS + n) * DQK + cb + 4 * g) = w;
            }
        } else {
            const int cbase = cot * 16 - 64;
            #pragma unroll
            for (int nt = 0; nt < 2; ++nt) {
                f32x4 a = nt ? a1 : a0;
                int n = n0 + 16 * nt + lm;
                int n64 = n >> 6, half = (n >> 5) & 1, nin = n & 31;
                #pragma unroll
                for (int r = 0; r < 4; ++r) {
                    int c = cbase + 4 * g + r;
                    size_t off = (((size_t)b * 16 + (c >> 4)) * 64 + n64) * 1024
                               + (size_t)half * 512 + (c & 15) * 32 + nin;
                    *reinterpret_cast<unsigned short*>(vb + off) = f2bf1(a[r]);
                }
            }
        }
    }
}

// ---------------- Kernel 2: cooperative MFMA flash (R8) + hoisted P-reads ----------------
__global__ __launch_bounds__(512) void flash_pam_kernel(
    const __hip_bfloat16* __restrict__ qb, const __hip_bfloat16* __restrict__ kb,
    const __hip_bfloat16* __restrict__ vb, const float* __restrict__ x,
    const float* __restrict__ gamma, float* __restrict__ out)
{
    __shared__ alignas(16) unsigned char Pl[2][8192];
    __shared__ float lred[4][4][16];   // [kt][mt][lm]

    const int tid  = threadIdx.x;
    const int wave = tid >> 6;
    const int lane = tid & 63;
    const int g    = lane >> 4;
    const int lm   = lane & 15;
    const int bid  = blockIdx.x;
    const int b    = bid & 3;
    const int m0   = (bid >> 2) * 64;
    const int kt   = wave & 3;
    const int mtA  = (wave >> 2) * 2;
    const unsigned swz = (unsigned)(lm & 7) << 4;

    const bf16x8 qfA = *reinterpret_cast<const bf16x8*>(
        qb + ((size_t)b * NPOS + m0 + 16 * mtA + lm) * DQK + 8 * g);
    const bf16x8 qfB = *reinterpret_cast<const bf16x8*>(
        qb + ((size_t)b * NPOS + m0 + 16 * mtA + 16 + lm) * DQK + 8 * g);

    const __hip_bfloat16* kbb = kb + (size_t)b * NPOS * DQK;
    const int koff0 = (16 * kt + lm) * DQK + 8 * g;           // + t*2048
    const __hip_bfloat16* vbb = vb + (size_t)b * 16 * 64 * 1024;
    int vfb[4];                                                // + t*1024
    #pragma unroll
    for (int cti = 0; cti < 2; ++cti)
        #pragma unroll
        for (int kc = 0; kc < 2; ++kc)
            vfb[2 * cti + kc] = (2 * wave + cti) * 65536 + kc * 512 + lm * 32 + 8 * g;

    const unsigned wbA = (unsigned)(16 * mtA + lm) * 128
                       + (((unsigned)(32 * kt + 8 * g)) ^ swz);
    const unsigned wbB = wbA + 16 * 128;

    unsigned char* P0 = &Pl[0][0];
    unsigned char* P1 = &Pl[1][0];

    f32x4 acc[2][4];
    #pragma unroll
    for (int i = 0; i < 2; ++i)
        #pragma unroll
        for (int j = 0; j < 4; ++j) acc[i][j] = (f32x4){0.f, 0.f, 0.f, 0.f};
    float lsA = 0.f, lsB = 0.f;

#define LOADK(dst, tk_) \
    dst = *reinterpret_cast<const bf16x8*>(kbb + koff0 + (tk_) * 2048);

#define LOADV(dst, tv_) { \
    _Pragma("unroll") for (int f = 0; f < 4; ++f) \
        dst[f] = *reinterpret_cast<const bf16x8*>(vbb + vfb[f] + (tv_) * 1024); }

#define QKW(KU, PW) { \
    f32x4 zb = {QB2, QB2, QB2, QB2}; \
    f32x4 sA = __builtin_amdgcn_mfma_f32_16x16x32_bf16(KU, qfA, zb, 0, 0, 0); \
    f32x4 sB = __builtin_amdgcn_mfma_f32_16x16x32_bf16(KU, qfB, zb, 0, 0, 0); \
    { float p0 = exp2f(sA[0]), p1 = exp2f(sA[1]); \
      float p2 = exp2f(sA[2]), p3 = exp2f(sA[3]); \
      lsA += (p0 + p1) + (p2 + p3); \
      uint2 w; w.x = pack_bf2(p0, p1); w.y = pack_bf2(p2, p3); \
      *reinterpret_cast<uint2*>((PW) + wbA) = w; } \
    { float p0 = exp2f(sB[0]), p1 = exp2f(sB[1]); \
      float p2 = exp2f(sB[2]), p3 = exp2f(sB[3]); \
      lsB += (p0 + p1) + (p2 + p3); \
      uint2 w; w.x = pack_bf2(p0, p1); w.y = pack_bf2(p2, p3); \
      *reinterpret_cast<uint2*>((PW) + wbB) = w; } }

// tail-only variant (reads inside)
#define PVt(PR, VR) { \
    _Pragma("unroll") for (int kc = 0; kc < 2; ++kc) { \
        bf16x8 pf[4]; \
        _Pragma("unroll") for (int mt = 0; mt < 4; ++mt) \
            pf[mt] = *reinterpret_cast<const bf16x8*>( \
                (PR) + (unsigned)(16 * mt + lm) * 128 \
                     + (((unsigned)(kc * 64 + 16 * g)) ^ swz)); \
        __builtin_amdgcn_s_setprio(1); \
        _Pragma("unroll") for (int cti = 0; cti < 2; ++cti) \
            _Pragma("unroll") for (int mt = 0; mt < 4; ++mt) \
                acc[cti][mt] = __builtin_amdgcn_mfma_f32_16x16x32_bf16( \
                    VR[2 * cti + kc], pf[mt], acc[cti][mt], 0, 0, 0); \
        __builtin_amdgcn_s_setprio(0); } }

// BODY(t): hoist P ds_reads first (complete under QK+exp2); then global
// prefetch V(t+1)/K(t+2); QK(t+1)->PW; PV(t) MFMAs; lgkm-only barrier.
#define BODY(t_, PR, PW, VR, VL, KU, KL) { \
    bf16x8 pf[2][4]; \
    _Pragma("unroll") for (int kc = 0; kc < 2; ++kc) \
        _Pragma("unroll") for (int mt = 0; mt < 4; ++mt) \
            pf[kc][mt] = *reinterpret_cast<const bf16x8*>( \
                (PR) + (unsigned)(16 * mt + lm) * 128 \
                     + (((unsigned)(kc * 64 + 16 * g)) ^ swz)); \
    { int tv = (t_) + 1; if (tv > 63) tv = 63; LOADV(VL, tv); } \
    { int tk2 = (t_) + 2; if (tk2 > 63) tk2 = 63; LOADK(KL, tk2); } \
    QKW(KU, PW); \
    __builtin_amdgcn_s_setprio(1); \
    _Pragma("unroll") for (int kc = 0; kc < 2; ++kc) \
        _Pragma("unroll") for (int cti = 0; cti < 2; ++cti) \
            _Pragma("unroll") for (int mt = 0; mt < 4; ++mt) \
                acc[cti][mt] = __builtin_amdgcn_mfma_f32_16x16x32_bf16( \
                    VR[2 * cti + kc], pf[kc][mt], acc[cti][mt], 0, 0, 0); \
    __builtin_amdgcn_s_setprio(0); \
    lds_barrier(); }

    // prologue
    bf16x8 kA, kB, vA[4], vB[4];
    LOADK(kA, 0);
    LOADV(vA, 0);
    LOADK(kB, 1);
    QKW(kA, P0);
    lds_barrier();

    for (int it = 0; it < 31; ++it) {
        BODY(2 * it,     P0, P1, vA, vB, kB, kA);
        BODY(2 * it + 1, P1, P0, vB, vA, kA, kB);
    }
    BODY(62, P0, P1, vA, vB, kB, kA);
    PVt(P1, vB);   // t = 63

    // merge per-subtile l partials
    lsA += __shfl_xor(lsA, 16); lsA += __shfl_xor(lsA, 32);
    lsB += __shfl_xor(lsB, 16); lsB += __shfl_xor(lsB, 32);
    if (lane < 16) {
        lred[kt][mtA][lm]     = lsA;
        lred[kt][mtA + 1][lm] = lsB;
    }
    __syncthreads();

    float linv[4];
    #pragma unroll
    for (int mt = 0; mt < 4; ++mt)
        linv[mt] = 1.f / (lred[0][mt][lm] + lred[1][mt][lm]
                        + lred[2][mt][lm] + lred[3][mt][lm]);

    const float gmv = gamma[0];
    #pragma unroll
    for (int cti = 0; cti < 2; ++cti)
        #pragma unroll
        for (int mt = 0; mt < 4; ++mt)
            #pragma unroll
            for (int r = 0; r < 4; ++r) {
                int c = 32 * wave + 16 * cti + 4 * g + r;
                size_t idx = ((size_t)b * CH + c) * NPOS + m0 + 16 * mt + lm;
                out[idx] = gmv * (acc[cti][mt][r] * linv[mt]) + x[idx];
            }
#undef BODY
#undef PVt
#undef QKW
#undef LOADV
#undef LOADK
}

extern "C" void kernel_launch(void* const* d_in, const int* in_sizes, int n_in,
                              void* d_out, int out_size, void* d_ws, size_t ws_size,
                              hipStream_t stream) {
    const float* x  = (const float*)d_in[0];
    const float* Wq = (const float*)d_in[1];
    const float* bq = (const float*)d_in[2];
    const float* Wk = (const float*)d_in[3];
    const float* bk = (const float*)d_in[4];
    const float* Wv = (const float*)d_in[5];
    const float* bv = (const float*)d_in[6];
    const float* gm = (const float*)d_in[7];
    float* out = (float*)d_out;

    __hip_bfloat16* qbuf = (__hip_bfloat16*)d_ws;
    __hip_bfloat16* kbuf = qbuf + (size_t)BATCH * NPOS * DQK;      // +1MB
    __hip_bfloat16* vbuf = kbuf + (size_t)BATCH * NPOS * DQK;      // +1MB
    __hip_bfloat16* wbf  = vbuf + (size_t)BATCH * CH * NPOS;       // +8MB
    float* bcat = (float*)(wbf + 320 * 256);                       // +160KB

    conv_w<<<dim3(320), 256, 0, stream>>>(Wq, bq, Wk, bk, Wv, bv, wbf, bcat);
    qkv_proj_mfma<<<dim3(NPOS / 32, BATCH), 256, 0, stream>>>(
        x, wbf, bcat, qbuf, kbuf, vbuf);
    flash_pam_kernel<<<dim3(NPOS / 64 * BATCH), 512, 0, stream>>>(
        qbuf, kbuf, vbuf, x, gm, out);
}